// Round 5
// baseline (1723.606 us; speedup 1.0000x reference)
//
#include <hip/hip_runtime.h>

// ---------------------------------------------------------------------------
// LSTM forecaster: 2-layer encoder (T=20) + 2-layer decoder (T=30, feedback).
// B=16384, H=128, F=10. R5: 512 blocks x 32 batch, 256 THREADS (4 waves).
// Empirical allocator rule: cap = 256 / max(attr_min_waves, wg_waves/4).
// 4-wave workgroup + waves_per_eu(1) -> cap 256 -> live set (~175) fits, no
// spill (R1-R4: 8-wave wg forced cap<=128 -> 520-670 MB scratch writes).
// Wave w owns j-tiles {w, w+4} x gates {i,f,g,o} (n = q*128+j) x 2 m-tiles.
// ---------------------------------------------------------------------------

typedef __attribute__((ext_vector_type(8))) short short8;   // 8 x bf16 frag
typedef __attribute__((ext_vector_type(4))) float float4v;  // 4 x f32 acc

#define MFMA16(a, b, c) __builtin_amdgcn_mfma_f32_16x16x32_bf16((a), (b), (c), 0, 0, 0)

__device__ __forceinline__ unsigned short f2bf(float x) {
    unsigned u = __builtin_bit_cast(unsigned, x);
    unsigned r = (u + 0x7FFFu + ((u >> 16) & 1u)) >> 16;  // RNE
    return (unsigned short)r;
}
__device__ __forceinline__ float bf2f(unsigned short b) {
    unsigned u = ((unsigned)b) << 16;
    return __builtin_bit_cast(float, u);
}

#if __has_builtin(__builtin_amdgcn_exp2f)
__device__ __forceinline__ float vexp2(float x) { return __builtin_amdgcn_exp2f(x); }
#else
__device__ __forceinline__ float vexp2(float x) { return exp2f(x); }
#endif
#if __has_builtin(__builtin_amdgcn_rcpf)
__device__ __forceinline__ float vrcp(float x) { return __builtin_amdgcn_rcpf(x); }
#else
__device__ __forceinline__ float vrcp(float x) { return 1.0f / x; }
#endif

__device__ __forceinline__ float sigm(float x) {
    return vrcp(1.0f + vexp2(x * -1.442695040888963f));
}
__device__ __forceinline__ float tanh_(float x) {
    return 1.0f - 2.0f * vrcp(1.0f + vexp2(x * 2.885390081777927f));
}

// ---------------------------------------------------------------------------
// prep kernel: fp32 weights -> bf16, concatenated per-layer [Wih | Whh],
// Wih0 padded 10->32; biases summed AND transposed to [set][j][q] float4;
// decoder-y weights transposed to [j][8].
// ws layout: We0[512][160] | We1[512][256] | Wd0[512][128] | Wd1[512][256]
//            (bf16, 819200 B) | bsT[4][128][4] f32 (8 KB) | wyT[128][8] f32 (4 KB)
// ---------------------------------------------------------------------------
__global__ void prep_kernel(const float* __restrict__ eWih0, const float* __restrict__ eWhh0,
                            const float* __restrict__ ebih0, const float* __restrict__ ebhh0,
                            const float* __restrict__ eWih1, const float* __restrict__ eWhh1,
                            const float* __restrict__ ebih1, const float* __restrict__ ebhh1,
                            const float* __restrict__ dWih0, const float* __restrict__ dWhh0,
                            const float* __restrict__ dbih0, const float* __restrict__ dbhh0,
                            const float* __restrict__ dWih1, const float* __restrict__ dWhh1,
                            const float* __restrict__ dbih1, const float* __restrict__ dbhh1,
                            void* __restrict__ ws)
{
    int i = blockIdx.x * 256 + threadIdx.x;
    short* We0 = (short*)ws;
    short* We1 = We0 + 512 * 160;
    short* Wd0 = We1 + 512 * 256;
    short* Wd1 = Wd0 + 512 * 128;
    float* bsT = (float*)((char*)ws + 819200);
    float* wyT = bsT + 2048;
    const int N0 = 512 * 160, N1 = 512 * 256, N2 = 512 * 128, N3 = 512 * 256;
    if (i < N0) {
        int n = i / 160, k = i - n * 160;
        float v = (k < 32) ? (k < 10 ? eWih0[n * 10 + k] : 0.0f) : eWhh0[n * 128 + (k - 32)];
        We0[i] = (short)f2bf(v);
    } else if (i < N0 + N1) {
        int ii = i - N0, n = ii >> 8, k = ii & 255;
        float v = (k < 128) ? eWih1[n * 128 + k] : eWhh1[n * 128 + (k - 128)];
        We1[ii] = (short)f2bf(v);
    } else if (i < N0 + N1 + N2) {
        int ii = i - (N0 + N1);
        Wd0[ii] = (short)f2bf(dWhh0[ii]);
    } else if (i < N0 + N1 + N2 + N3) {
        int ii = i - (N0 + N1 + N2), n = ii >> 8, k = ii & 255;
        float v = (k < 128) ? dWih1[n * 128 + k] : dWhh1[n * 128 + (k - 128)];
        Wd1[ii] = (short)f2bf(v);
    } else if (i < N0 + N1 + N2 + N3 + 2048) {
        int ii = i - (N0 + N1 + N2 + N3);
        int set = ii >> 9, r = ii & 511, j = r >> 2, q = r & 3;
        int g = q * 128 + j;
        float v = (set == 0) ? ebih0[g] + ebhh0[g]
                : (set == 1) ? ebih1[g] + ebhh1[g]
                : (set == 2) ? dbih0[g] + dbhh0[g]
                             : dbih1[g] + dbhh1[g];
        bsT[ii] = v;
    } else if (i < N0 + N1 + N2 + N3 + 2048 + 1024) {
        int ii = i - (N0 + N1 + N2 + N3 + 2048);
        int j = ii >> 3, e = ii & 7, q = e >> 1, cc = e & 1;
        wyT[ii] = dWih0[(q * 128 + j) * 2 + cc];
    }
}

// ---------------------------------------------------------------------------
// main kernel (per block: 32 batch rows, 4 waves of 64)
// LDS h-buffers (32 rows x 16 chunks of 16B): slot(m,kc) = m*16 + (kc ^ (m&15))
// xbuf (32 rows x 4 chunks): slot(m,kc) = m*4 + (kc ^ (m&3))
// Wave w: m-tiles {0,1}; n-tiles {q*8 + jt} for q=0..3 (gate), jt in {w, w+4}
// A-frag: A[m = mt*16 + (lane&15)][k = (lane>>4)*8 + i]
// B-frag: B row n = q*128 + jtile*16 + (lane&15), k-chunk (lane>>4)
// C/D:    col = lane&15 (hidden unit within j-tile), row = (lane>>4)*4 + reg
// acc index: [q*2 + jt_idx][mt]
// ---------------------------------------------------------------------------

template <int NKT>
__device__ __forceinline__ void mma8(float4v acc[8][2], const short8* __restrict__ hb,
                                     const char* __restrict__ wb, const unsigned* wo,
                                     int woff, int nib, int quad)
{
#pragma unroll
    for (int kk = 0; kk < NKT; ++kk) {
        int sx = ((kk * 4 + quad) ^ nib) + nib * 16;
        short8 a0 = hb[sx];
        short8 a1 = hb[256 + sx];
#pragma unroll
        for (int i = 0; i < 8; ++i) {
            short8 b = *(const short8*)(wb + (wo[i] + woff + kk * 64));
            acc[i][0] = MFMA16(a0, b, acc[i][0]);
            acc[i][1] = MFMA16(a1, b, acc[i][1]);
        }
    }
}

// elementwise LSTM cell update; writes h (bf16) to hdst with swizzled layout
template <bool DEC0>
__device__ __forceinline__ void cell_updateN(float4v acc[8][2], const float* __restrict__ bsTset,
                                             float* cst, unsigned short* __restrict__ hdst,
                                             const float* __restrict__ ybuf,
                                             const float* __restrict__ wyT,
                                             int j0, int quad)
{
#pragma unroll
    for (int jt = 0; jt < 2; ++jt) {
        int j = j0 + jt * 64;
        float4v bv = *(const float4v*)(bsTset + j * 4);
        float4v wy0 = {0, 0, 0, 0}, wy1 = {0, 0, 0, 0};
        if (DEC0) {
            wy0 = *(const float4v*)(wyT + j * 8);
            wy1 = *(const float4v*)(wyT + j * 8 + 4);
        }
        int kc = j >> 3;
        int jl = j & 7;
#pragma unroll
        for (int mt = 0; mt < 2; ++mt) {
#pragma unroll
            for (int r = 0; r < 4; ++r) {
                float gi = acc[0 + jt][mt][r] + bv[0];
                float gf = acc[2 + jt][mt][r] + bv[1];
                float gg = acc[4 + jt][mt][r] + bv[2];
                float go = acc[6 + jt][mt][r] + bv[3];
                int m = mt * 16 + quad * 4 + r;
                if (DEC0) {
                    float y0 = ybuf[2 * m], y1 = ybuf[2 * m + 1];
                    gi += y0 * wy0[0] + y1 * wy0[1];
                    gf += y0 * wy0[2] + y1 * wy0[3];
                    gg += y0 * wy1[0] + y1 * wy1[1];
                    go += y0 * wy1[2] + y1 * wy1[3];
                }
                float si = sigm(gi);
                float sf = sigm(gf);
                float tg = tanh_(gg);
                float so = sigm(go);
                float c = sf * cst[jt * 8 + mt * 4 + r] + si * tg;
                cst[jt * 8 + mt * 4 + r] = c;
                float h = so * tanh_(c);
                int slot = m * 16 + (kc ^ (m & 15));
                hdst[slot * 8 + jl] = f2bf(h);
            }
        }
    }
}

__global__ void __attribute__((amdgpu_flat_work_group_size(256, 256),
                               amdgpu_waves_per_eu(1)))
lstm_main(
    const float* __restrict__ hist,
    const float* __restrict__ headW, const float* __restrict__ headB,
    const int* __restrict__ futlen, const void* __restrict__ ws,
    float* __restrict__ out)
{
    __shared__ short8 h0buf[512];  // 32 rows x 16 chunks, swizzled
    __shared__ short8 h1buf[512];
    __shared__ short8 xbuf[128];   // 32 rows x 4 chunks, swizzled
    __shared__ float ybuf[64];     // [32][2]

    const char* wsb = (const char*)ws;
    const char* We0 = wsb;                       // rows of 320 B
    const char* We1 = wsb + 512 * 160 * 2;       // rows of 512 B
    const char* Wd0 = We1 + 512 * 256 * 2;       // rows of 256 B
    const char* Wd1 = Wd0 + 512 * 128 * 2;       // rows of 512 B
    const float* bsT = (const float*)(wsb + 819200);
    const float* wyT = bsT + 2048;

    const int tid = threadIdx.x;
    const int w = tid >> 6;          // wave 0..3
    const int lane = tid & 63;
    const int quad = lane >> 4;
    const int nib = lane & 15;
    const int b0 = blockIdx.x * 32;
    const int TFUT = *futlen;
    const int j0 = 16 * w + nib;     // first of the wave's two hidden units

    // zero-init LDS state
    h0buf[tid] = (short8)0;
    h0buf[256 + tid] = (short8)0;
    h1buf[tid] = (short8)0;
    h1buf[256 + tid] = (short8)0;
    if (tid < 128) xbuf[tid] = (short8)0;
    if (tid < 64) ybuf[tid] = 0.0f;

    float c0[16], c1[16];
#pragma unroll
    for (int i = 0; i < 16; ++i) { c0[i] = 0.0f; c1[i] = 0.0f; }

    // 32-bit B-row byte offsets, 8 per matrix: row = q*128 + (w+4*jt)*16 + nib
    unsigned eo0[8], eo1[8];
#pragma unroll
    for (int q = 0; q < 4; ++q)
#pragma unroll
        for (int jt = 0; jt < 2; ++jt) {
            unsigned row = q * 128u + (w + 4u * jt) * 16u + nib;
            eo0[q * 2 + jt] = row * 320u + quad * 16u;
            eo1[q * 2 + jt] = row * 512u + quad * 16u;
        }
    __syncthreads();

    // ================= ENCODER =================
    for (int t = 0; t < 20; ++t) {
        // stage hist[.., t, :] -> xbuf (bf16, zero-padded to K=32)
        if (tid < 64) {
            int m = tid & 31, part = tid >> 5;  // part: k-chunk 0 or 1
            const float* hp = hist + ((size_t)((b0 + m) * 20 + t)) * 10;
            float v[8];
            if (part == 0) {
#pragma unroll
                for (int i = 0; i < 8; ++i) v[i] = hp[i];
            } else {
                v[0] = hp[8]; v[1] = hp[9];
#pragma unroll
                for (int i = 2; i < 8; ++i) v[i] = 0.0f;
            }
            short8 pk;
#pragma unroll
            for (int i = 0; i < 8; ++i) pk[i] = (short)f2bf(v[i]);
            xbuf[m * 4 + (part ^ (m & 3))] = pk;
        }
        __syncthreads();

        // ---- layer 0: gates = x@Wih0^T + h0@Whh0^T ----
        {
            float4v acc[8][2];
#pragma unroll
            for (int i = 0; i < 8; ++i) {
                acc[i][0] = (float4v){0.f, 0.f, 0.f, 0.f};
                acc[i][1] = (float4v){0.f, 0.f, 0.f, 0.f};
            }
            // x part (k 0..31) from xbuf
            {
                int sxx = (quad ^ (nib & 3)) + nib * 4;
                short8 a0 = xbuf[sxx];
                short8 a1 = xbuf[64 + sxx];
#pragma unroll
                for (int i = 0; i < 8; ++i) {
                    short8 b = *(const short8*)(We0 + eo0[i]);
                    acc[i][0] = MFMA16(a0, b, acc[i][0]);
                    acc[i][1] = MFMA16(a1, b, acc[i][1]);
                }
            }
            // h part (W k 32..159, bytes 64..) from h0buf
            mma8<4>(acc, h0buf, We0, eo0, 64, nib, quad);
            __syncthreads();
            cell_updateN<false>(acc, bsT + 0 * 512, c0, (unsigned short*)h0buf,
                                nullptr, nullptr, j0, quad);
        }
        __syncthreads();

        // ---- layer 1: gates = h0new@Wih1^T + h1@Whh1^T ----
        {
            float4v acc[8][2];
#pragma unroll
            for (int i = 0; i < 8; ++i) {
                acc[i][0] = (float4v){0.f, 0.f, 0.f, 0.f};
                acc[i][1] = (float4v){0.f, 0.f, 0.f, 0.f};
            }
            mma8<4>(acc, h0buf, We1, eo1, 0, nib, quad);
            mma8<4>(acc, h1buf, We1, eo1, 256, nib, quad);
            __syncthreads();
            cell_updateN<false>(acc, bsT + 1 * 512, c1, (unsigned short*)h1buf,
                                nullptr, nullptr, j0, quad);
        }
        __syncthreads();
    }

    // ================= DECODER =================
    unsigned do0[8], do1[8];
#pragma unroll
    for (int q = 0; q < 4; ++q)
#pragma unroll
        for (int jt = 0; jt < 2; ++jt) {
            unsigned row = q * 128u + (w + 4u * jt) * 16u + nib;
            do0[q * 2 + jt] = row * 256u + quad * 16u;
            do1[q * 2 + jt] = row * 512u + quad * 16u;
        }

    for (int t = 0; t < TFUT; ++t) {
        // ---- dec layer 0: gates = y@dWih0^T (VALU) + h0@dWhh0^T (MFMA) ----
        {
            float4v acc[8][2];
#pragma unroll
            for (int i = 0; i < 8; ++i) {
                acc[i][0] = (float4v){0.f, 0.f, 0.f, 0.f};
                acc[i][1] = (float4v){0.f, 0.f, 0.f, 0.f};
            }
            mma8<4>(acc, h0buf, Wd0, do0, 0, nib, quad);
            __syncthreads();
            cell_updateN<true>(acc, bsT + 2 * 512, c0, (unsigned short*)h0buf,
                               ybuf, wyT, j0, quad);
        }
        __syncthreads();

        // ---- dec layer 1 ----
        {
            float4v acc[8][2];
#pragma unroll
            for (int i = 0; i < 8; ++i) {
                acc[i][0] = (float4v){0.f, 0.f, 0.f, 0.f};
                acc[i][1] = (float4v){0.f, 0.f, 0.f, 0.f};
            }
            mma8<4>(acc, h0buf, Wd1, do1, 0, nib, quad);
            mma8<4>(acc, h1buf, Wd1, do1, 256, nib, quad);
            __syncthreads();
            cell_updateN<false>(acc, bsT + 3 * 512, c1, (unsigned short*)h1buf,
                                nullptr, nullptr, j0, quad);
        }
        __syncthreads();

        // ---- head: y = h1new @ headW^T + headB; emit output & feedback ----
        if (tid < 64) {
            int m = tid & 31, jj = tid >> 5;
            const float4v* hw = (const float4v*)(headW + jj * 128);
            float dot = headB[jj];
            int mk = m & 15;
#pragma unroll
            for (int kc = 0; kc < 16; ++kc) {
                short8 ch = h1buf[m * 16 + (kc ^ mk)];
                float4v w0 = hw[kc * 2], w1 = hw[kc * 2 + 1];
                dot += bf2f((unsigned short)ch[0]) * w0[0];
                dot += bf2f((unsigned short)ch[1]) * w0[1];
                dot += bf2f((unsigned short)ch[2]) * w0[2];
                dot += bf2f((unsigned short)ch[3]) * w0[3];
                dot += bf2f((unsigned short)ch[4]) * w1[0];
                dot += bf2f((unsigned short)ch[5]) * w1[1];
                dot += bf2f((unsigned short)ch[6]) * w1[2];
                dot += bf2f((unsigned short)ch[7]) * w1[3];
            }
            ybuf[2 * m + jj] = dot;
            out[((size_t)(b0 + m) * TFUT + t) * 2 + jj] = dot;
        }
        __syncthreads();
    }
}

extern "C" void kernel_launch(void* const* d_in, const int* in_sizes, int n_in,
                              void* d_out, int out_size, void* d_ws, size_t ws_size,
                              hipStream_t stream)
{
    const float* hist   = (const float*)d_in[0];
    const float* eWih0  = (const float*)d_in[1];
    const float* eWhh0  = (const float*)d_in[2];
    const float* ebih0  = (const float*)d_in[3];
    const float* ebhh0  = (const float*)d_in[4];
    const float* eWih1  = (const float*)d_in[5];
    const float* eWhh1  = (const float*)d_in[6];
    const float* ebih1  = (const float*)d_in[7];
    const float* ebhh1  = (const float*)d_in[8];
    const float* dWih0  = (const float*)d_in[9];
    const float* dWhh0  = (const float*)d_in[10];
    const float* dbih0  = (const float*)d_in[11];
    const float* dbhh0  = (const float*)d_in[12];
    const float* dWih1  = (const float*)d_in[13];
    const float* dWhh1  = (const float*)d_in[14];
    const float* dbih1  = (const float*)d_in[15];
    const float* dbhh1  = (const float*)d_in[16];
    const float* headW  = (const float*)d_in[17];
    const float* headB  = (const float*)d_in[18];
    const int*   futlen = (const int*)d_in[19];

    // weights 409600 bf16 + bsT 2048 f32 + wyT 1024 f32 -> 412672 work items
    prep_kernel<<<1612, 256, 0, stream>>>(eWih0, eWhh0, ebih0, ebhh0,
                                          eWih1, eWhh1, ebih1, ebhh1,
                                          dWih0, dWhh0, dbih0, dbhh0,
                                          dWih1, dWhh1, dbih1, dbhh1, d_ws);

    lstm_main<<<512, 256, 0, stream>>>(hist, headW, headB, futlen,
                                       d_ws, (float*)d_out);
}

// Round 6
// 1467.333 us; speedup vs baseline: 1.1747x; 1.1747x over previous
//
#include <hip/hip_runtime.h>

// ---------------------------------------------------------------------------
// LSTM forecaster: 2-layer encoder (T=20) + 2-layer decoder (T=30, feedback).
// B=16384, H=128, F=10. R6: 512 blocks x 32 batch, 512 threads (8 waves),
// wave = 2 m-tiles x 4 n-tiles (acc 32 regs, c 16) -> live ~120 fits the
// cap-128 that an 8-wave workgroup implies (R1-R5 established:
// cap = 256 / max(attr_min_waves, wg_waves/4)). waves_per_eu(2) pins it.
// Pressure trims: unroll 2 on kk (<=8 B-frags in flight), dec-l1 offsets
// alias enc-l1 (same 512B row stride), unroll 1 on t-loops.
// ---------------------------------------------------------------------------

typedef __attribute__((ext_vector_type(8))) short short8;   // 8 x bf16 frag
typedef __attribute__((ext_vector_type(4))) float float4v;  // 4 x f32 acc

#define MFMA16(a, b, c) __builtin_amdgcn_mfma_f32_16x16x32_bf16((a), (b), (c), 0, 0, 0)

__device__ __forceinline__ unsigned short f2bf(float x) {
    unsigned u = __builtin_bit_cast(unsigned, x);
    unsigned r = (u + 0x7FFFu + ((u >> 16) & 1u)) >> 16;  // RNE
    return (unsigned short)r;
}
__device__ __forceinline__ float bf2f(unsigned short b) {
    unsigned u = ((unsigned)b) << 16;
    return __builtin_bit_cast(float, u);
}

#if __has_builtin(__builtin_amdgcn_exp2f)
__device__ __forceinline__ float vexp2(float x) { return __builtin_amdgcn_exp2f(x); }
#else
__device__ __forceinline__ float vexp2(float x) { return exp2f(x); }
#endif
#if __has_builtin(__builtin_amdgcn_rcpf)
__device__ __forceinline__ float vrcp(float x) { return __builtin_amdgcn_rcpf(x); }
#else
__device__ __forceinline__ float vrcp(float x) { return 1.0f / x; }
#endif

__device__ __forceinline__ float sigm(float x) {
    return vrcp(1.0f + vexp2(x * -1.442695040888963f));
}
__device__ __forceinline__ float tanh_(float x) {
    return 1.0f - 2.0f * vrcp(1.0f + vexp2(x * 2.885390081777927f));
}

// ---------------------------------------------------------------------------
// prep kernel: fp32 weights -> bf16, concatenated per-layer [Wih | Whh],
// Wih0 padded 10->32; biases summed AND transposed to [set][j][q] float4;
// decoder-y weights transposed to [j][8].
// ws layout: We0[512][160] | We1[512][256] | Wd0[512][128] | Wd1[512][256]
//            (bf16, 819200 B) | bsT[4][128][4] f32 (8 KB) | wyT[128][8] f32 (4 KB)
// ---------------------------------------------------------------------------
__global__ void prep_kernel(const float* __restrict__ eWih0, const float* __restrict__ eWhh0,
                            const float* __restrict__ ebih0, const float* __restrict__ ebhh0,
                            const float* __restrict__ eWih1, const float* __restrict__ eWhh1,
                            const float* __restrict__ ebih1, const float* __restrict__ ebhh1,
                            const float* __restrict__ dWih0, const float* __restrict__ dWhh0,
                            const float* __restrict__ dbih0, const float* __restrict__ dbhh0,
                            const float* __restrict__ dWih1, const float* __restrict__ dWhh1,
                            const float* __restrict__ dbih1, const float* __restrict__ dbhh1,
                            void* __restrict__ ws)
{
    int i = blockIdx.x * 256 + threadIdx.x;
    short* We0 = (short*)ws;
    short* We1 = We0 + 512 * 160;
    short* Wd0 = We1 + 512 * 256;
    short* Wd1 = Wd0 + 512 * 128;
    float* bsT = (float*)((char*)ws + 819200);
    float* wyT = bsT + 2048;
    const int N0 = 512 * 160, N1 = 512 * 256, N2 = 512 * 128, N3 = 512 * 256;
    if (i < N0) {
        int n = i / 160, k = i - n * 160;
        float v = (k < 32) ? (k < 10 ? eWih0[n * 10 + k] : 0.0f) : eWhh0[n * 128 + (k - 32)];
        We0[i] = (short)f2bf(v);
    } else if (i < N0 + N1) {
        int ii = i - N0, n = ii >> 8, k = ii & 255;
        float v = (k < 128) ? eWih1[n * 128 + k] : eWhh1[n * 128 + (k - 128)];
        We1[ii] = (short)f2bf(v);
    } else if (i < N0 + N1 + N2) {
        int ii = i - (N0 + N1);
        Wd0[ii] = (short)f2bf(dWhh0[ii]);
    } else if (i < N0 + N1 + N2 + N3) {
        int ii = i - (N0 + N1 + N2), n = ii >> 8, k = ii & 255;
        float v = (k < 128) ? dWih1[n * 128 + k] : dWhh1[n * 128 + (k - 128)];
        Wd1[ii] = (short)f2bf(v);
    } else if (i < N0 + N1 + N2 + N3 + 2048) {
        int ii = i - (N0 + N1 + N2 + N3);
        int set = ii >> 9, r = ii & 511, j = r >> 2, q = r & 3;
        int g = q * 128 + j;
        float v = (set == 0) ? ebih0[g] + ebhh0[g]
                : (set == 1) ? ebih1[g] + ebhh1[g]
                : (set == 2) ? dbih0[g] + dbhh0[g]
                             : dbih1[g] + dbhh1[g];
        bsT[ii] = v;
    } else if (i < N0 + N1 + N2 + N3 + 2048 + 1024) {
        int ii = i - (N0 + N1 + N2 + N3 + 2048);
        int j = ii >> 3, e = ii & 7, q = e >> 1, cc = e & 1;
        wyT[ii] = dWih0[(q * 128 + j) * 2 + cc];
    }
}

// ---------------------------------------------------------------------------
// main kernel (per block: 32 batch rows, 8 waves)
// LDS h-buffers (32 rows x 16 chunks of 16B): slot(m,kc) = m*16 + (kc ^ (m&15))
// xbuf (32 rows x 4 chunks): slot(m,kc) = m*4 + (kc ^ (m&3))
// Wave w: m-tiles {0,1}, n-tiles {w, w+8, w+16, w+24} (q = gate i/f/g/o)
// A-frag: A[m = mt*16 + (lane&15)][k = (lane>>4)*8 + i]
// B-frag: B row n = 16*(w+8q) + (lane&15), k-chunk (lane>>4)
// C/D:    col = lane&15 (gate unit), row = (lane>>4)*4 + reg (batch)
// ---------------------------------------------------------------------------

template <int NKT>
__device__ __forceinline__ void mma2(float4v acc[4][2], const short8* __restrict__ hb,
                                     const char* __restrict__ wb, const unsigned* wo,
                                     int woff, int nib, int quad)
{
#pragma unroll 2
    for (int kk = 0; kk < NKT; ++kk) {
        int sx = ((kk * 4 + quad) ^ nib) + nib * 16;
        short8 a0 = hb[sx];
        short8 a1 = hb[256 + sx];
        short8 b0 = *(const short8*)(wb + (wo[0] + woff + kk * 64));
        short8 b1 = *(const short8*)(wb + (wo[1] + woff + kk * 64));
        short8 b2 = *(const short8*)(wb + (wo[2] + woff + kk * 64));
        short8 b3 = *(const short8*)(wb + (wo[3] + woff + kk * 64));
        acc[0][0] = MFMA16(a0, b0, acc[0][0]);
        acc[0][1] = MFMA16(a1, b0, acc[0][1]);
        acc[1][0] = MFMA16(a0, b1, acc[1][0]);
        acc[1][1] = MFMA16(a1, b1, acc[1][1]);
        acc[2][0] = MFMA16(a0, b2, acc[2][0]);
        acc[2][1] = MFMA16(a1, b2, acc[2][1]);
        acc[3][0] = MFMA16(a0, b3, acc[3][0]);
        acc[3][1] = MFMA16(a1, b3, acc[3][1]);
    }
}

// elementwise LSTM cell update; writes h (bf16) to hdst with swizzled layout
template <bool DEC0>
__device__ __forceinline__ void cell_update2(float4v acc[4][2], float4v bv,
                                             float* cst, unsigned short* __restrict__ hdst,
                                             const float* __restrict__ ybuf,
                                             float4v wy0, float4v wy1,
                                             int j, int quad)
{
    int kc = j >> 3;
    int jl = j & 7;
#pragma unroll
    for (int mt = 0; mt < 2; ++mt) {
#pragma unroll
        for (int r = 0; r < 4; ++r) {
            float gi = acc[0][mt][r] + bv[0];
            float gf = acc[1][mt][r] + bv[1];
            float gg = acc[2][mt][r] + bv[2];
            float go = acc[3][mt][r] + bv[3];
            int m = mt * 16 + quad * 4 + r;
            if (DEC0) {
                float y0 = ybuf[2 * m], y1 = ybuf[2 * m + 1];
                gi += y0 * wy0[0] + y1 * wy0[1];
                gf += y0 * wy0[2] + y1 * wy0[3];
                gg += y0 * wy1[0] + y1 * wy1[1];
                go += y0 * wy1[2] + y1 * wy1[3];
            }
            float si = sigm(gi);
            float sf = sigm(gf);
            float tg = tanh_(gg);
            float so = sigm(go);
            float c = sf * cst[mt * 4 + r] + si * tg;
            cst[mt * 4 + r] = c;
            float h = so * tanh_(c);
            int slot = m * 16 + (kc ^ (m & 15));
            hdst[slot * 8 + jl] = f2bf(h);
        }
    }
}

__global__ void __attribute__((amdgpu_flat_work_group_size(512, 512), amdgpu_waves_per_eu(2)))
lstm_main(
    const float* __restrict__ hist,
    const float* __restrict__ headW, const float* __restrict__ headB,
    const int* __restrict__ futlen, const void* __restrict__ ws,
    float* __restrict__ out)
{
    __shared__ short8 h0buf[512];  // 32 rows x 16 chunks, swizzled
    __shared__ short8 h1buf[512];
    __shared__ short8 xbuf[128];   // 32 rows x 4 chunks, swizzled
    __shared__ float ybuf[64];     // [32][2]

    const char* wsb = (const char*)ws;
    const char* We0 = wsb;                       // rows of 320 B
    const char* We1 = wsb + 512 * 160 * 2;       // rows of 512 B
    const char* Wd0 = We1 + 512 * 256 * 2;       // rows of 256 B
    const char* Wd1 = Wd0 + 512 * 128 * 2;       // rows of 512 B
    const float* bsT = (const float*)(wsb + 819200);
    const float* wyT = bsT + 2048;

    const int tid = threadIdx.x;
    const int w = tid >> 6;
    const int lane = tid & 63;
    const int quad = lane >> 4;
    const int nib = lane & 15;
    const int b0 = blockIdx.x * 32;
    const int TFUT = *futlen;
    const int j = 16 * w + nib;

    // zero-init LDS state
    h0buf[tid] = (short8)0;
    h1buf[tid] = (short8)0;
    if (tid < 128) xbuf[tid] = (short8)0;
    if (tid < 64) ybuf[tid] = 0.0f;

    float c0[8], c1[8];
#pragma unroll
    for (int i = 0; i < 8; ++i) { c0[i] = 0.0f; c1[i] = 0.0f; }

    // 32-bit B-row byte offsets (per lane): row = 16*(w+8q)+nib, + quad*16
    // eo1 also serves decoder layer 1 (Wd1 has the same 512-B row stride).
    unsigned eo0[4], eo1[4];
#pragma unroll
    for (int q = 0; q < 4; ++q) {
        unsigned row = 16u * (w + 8 * q) + nib;
        eo0[q] = row * 320u + quad * 16u;
        eo1[q] = row * 512u + quad * 16u;
    }
    __syncthreads();

    // ================= ENCODER =================
#pragma unroll 1
    for (int t = 0; t < 20; ++t) {
        // stage hist[.., t, :] -> xbuf (bf16, zero-padded to K=32)
        if (tid < 64) {
            int m = tid & 31, part = tid >> 5;  // part: k-chunk 0 or 1
            const float* hp = hist + ((size_t)((b0 + m) * 20 + t)) * 10;
            float v[8];
            if (part == 0) {
#pragma unroll
                for (int i = 0; i < 8; ++i) v[i] = hp[i];
            } else {
                v[0] = hp[8]; v[1] = hp[9];
#pragma unroll
                for (int i = 2; i < 8; ++i) v[i] = 0.0f;
            }
            short8 pk;
#pragma unroll
            for (int i = 0; i < 8; ++i) pk[i] = (short)f2bf(v[i]);
            xbuf[m * 4 + (part ^ (m & 3))] = pk;
        }
        __syncthreads();

        // ---- layer 0: gates = x@Wih0^T + h0@Whh0^T ----
        {
            float4v acc[4][2];
#pragma unroll
            for (int q = 0; q < 4; ++q)
#pragma unroll
                for (int mt = 0; mt < 2; ++mt) acc[q][mt] = (float4v){0.f, 0.f, 0.f, 0.f};
            // x part (k 0..31) from xbuf
            {
                int sxx = (quad ^ (nib & 3)) + nib * 4;
                short8 a0 = xbuf[sxx];
                short8 a1 = xbuf[64 + sxx];
                short8 bq0 = *(const short8*)(We0 + eo0[0]);
                short8 bq1 = *(const short8*)(We0 + eo0[1]);
                short8 bq2 = *(const short8*)(We0 + eo0[2]);
                short8 bq3 = *(const short8*)(We0 + eo0[3]);
                acc[0][0] = MFMA16(a0, bq0, acc[0][0]);
                acc[0][1] = MFMA16(a1, bq0, acc[0][1]);
                acc[1][0] = MFMA16(a0, bq1, acc[1][0]);
                acc[1][1] = MFMA16(a1, bq1, acc[1][1]);
                acc[2][0] = MFMA16(a0, bq2, acc[2][0]);
                acc[2][1] = MFMA16(a1, bq2, acc[2][1]);
                acc[3][0] = MFMA16(a0, bq3, acc[3][0]);
                acc[3][1] = MFMA16(a1, bq3, acc[3][1]);
            }
            // h part (W k 32..159, bytes 64..) from h0buf
            mma2<4>(acc, h0buf, We0, eo0, 64, nib, quad);
            float4v bv = *(const float4v*)(bsT + 0 * 512 + j * 4);
            __syncthreads();
            cell_update2<false>(acc, bv, c0, (unsigned short*)h0buf, nullptr,
                                (float4v){0, 0, 0, 0}, (float4v){0, 0, 0, 0}, j, quad);
        }
        __syncthreads();

        // ---- layer 1: gates = h0new@Wih1^T + h1@Whh1^T ----
        {
            float4v acc[4][2];
#pragma unroll
            for (int q = 0; q < 4; ++q)
#pragma unroll
                for (int mt = 0; mt < 2; ++mt) acc[q][mt] = (float4v){0.f, 0.f, 0.f, 0.f};
            mma2<4>(acc, h0buf, We1, eo1, 0, nib, quad);
            mma2<4>(acc, h1buf, We1, eo1, 256, nib, quad);
            float4v bv = *(const float4v*)(bsT + 1 * 512 + j * 4);
            __syncthreads();
            cell_update2<false>(acc, bv, c1, (unsigned short*)h1buf, nullptr,
                                (float4v){0, 0, 0, 0}, (float4v){0, 0, 0, 0}, j, quad);
        }
        __syncthreads();
    }

    // ================= DECODER =================
    // Wd1 offsets == eo1 (same 512-B stride). Only Wd0 (256-B rows) is new.
    unsigned do0[4];
#pragma unroll
    for (int q = 0; q < 4; ++q) {
        unsigned row = 16u * (w + 8 * q) + nib;
        do0[q] = row * 256u + quad * 16u;
    }

#pragma unroll 1
    for (int t = 0; t < TFUT; ++t) {
        // ---- dec layer 0: gates = y@dWih0^T (VALU) + h0@dWhh0^T (MFMA) ----
        {
            float4v acc[4][2];
#pragma unroll
            for (int q = 0; q < 4; ++q)
#pragma unroll
                for (int mt = 0; mt < 2; ++mt) acc[q][mt] = (float4v){0.f, 0.f, 0.f, 0.f};
            mma2<4>(acc, h0buf, Wd0, do0, 0, nib, quad);
            float4v bv = *(const float4v*)(bsT + 2 * 512 + j * 4);
            float4v wy0 = *(const float4v*)(wyT + j * 8);
            float4v wy1 = *(const float4v*)(wyT + j * 8 + 4);
            __syncthreads();
            cell_update2<true>(acc, bv, c0, (unsigned short*)h0buf, ybuf, wy0, wy1, j, quad);
        }
        __syncthreads();

        // ---- dec layer 1 ----
        {
            float4v acc[4][2];
#pragma unroll
            for (int q = 0; q < 4; ++q)
#pragma unroll
                for (int mt = 0; mt < 2; ++mt) acc[q][mt] = (float4v){0.f, 0.f, 0.f, 0.f};
            mma2<4>(acc, h0buf, Wd1, eo1, 0, nib, quad);
            mma2<4>(acc, h1buf, Wd1, eo1, 256, nib, quad);
            float4v bv = *(const float4v*)(bsT + 3 * 512 + j * 4);
            __syncthreads();
            cell_update2<false>(acc, bv, c1, (unsigned short*)h1buf, nullptr,
                                (float4v){0, 0, 0, 0}, (float4v){0, 0, 0, 0}, j, quad);
        }
        __syncthreads();

        // ---- head: y = h1new @ headW^T + headB; emit output & feedback ----
        if (tid < 64) {
            int m = tid & 31, jj = tid >> 5;
            const float4v* hw = (const float4v*)(headW + jj * 128);
            float dot = headB[jj];
            int mk = m & 15;
#pragma unroll
            for (int kc = 0; kc < 16; ++kc) {
                short8 ch = h1buf[m * 16 + (kc ^ mk)];
                float4v w0 = hw[kc * 2], w1 = hw[kc * 2 + 1];
                dot += bf2f((unsigned short)ch[0]) * w0[0];
                dot += bf2f((unsigned short)ch[1]) * w0[1];
                dot += bf2f((unsigned short)ch[2]) * w0[2];
                dot += bf2f((unsigned short)ch[3]) * w0[3];
                dot += bf2f((unsigned short)ch[4]) * w1[0];
                dot += bf2f((unsigned short)ch[5]) * w1[1];
                dot += bf2f((unsigned short)ch[6]) * w1[2];
                dot += bf2f((unsigned short)ch[7]) * w1[3];
            }
            ybuf[2 * m + jj] = dot;
            out[((size_t)(b0 + m) * TFUT + t) * 2 + jj] = dot;
        }
        __syncthreads();
    }
}

extern "C" void kernel_launch(void* const* d_in, const int* in_sizes, int n_in,
                              void* d_out, int out_size, void* d_ws, size_t ws_size,
                              hipStream_t stream)
{
    const float* hist   = (const float*)d_in[0];
    const float* eWih0  = (const float*)d_in[1];
    const float* eWhh0  = (const float*)d_in[2];
    const float* ebih0  = (const float*)d_in[3];
    const float* ebhh0  = (const float*)d_in[4];
    const float* eWih1  = (const float*)d_in[5];
    const float* eWhh1  = (const float*)d_in[6];
    const float* ebih1  = (const float*)d_in[7];
    const float* ebhh1  = (const float*)d_in[8];
    const float* dWih0  = (const float*)d_in[9];
    const float* dWhh0  = (const float*)d_in[10];
    const float* dbih0  = (const float*)d_in[11];
    const float* dbhh0  = (const float*)d_in[12];
    const float* dWih1  = (const float*)d_in[13];
    const float* dWhh1  = (const float*)d_in[14];
    const float* dbih1  = (const float*)d_in[15];
    const float* dbhh1  = (const float*)d_in[16];
    const float* headW  = (const float*)d_in[17];
    const float* headB  = (const float*)d_in[18];
    const int*   futlen = (const int*)d_in[19];

    // weights 409600 bf16 + bsT 2048 f32 + wyT 1024 f32 -> 412672 work items
    prep_kernel<<<1612, 256, 0, stream>>>(eWih0, eWhh0, ebih0, ebhh0,
                                          eWih1, eWhh1, ebih1, ebhh1,
                                          dWih0, dWhh0, dbih0, dbhh0,
                                          dWih1, dWhh1, dbih1, dbhh1, d_ws);

    lstm_main<<<512, 512, 0, stream>>>(hist, headW, headB, futlen,
                                       d_ws, (float*)d_out);
}

// Round 8
// 946.718 us; speedup vs baseline: 1.8206x; 1.5499x over previous
//
#include <hip/hip_runtime.h>

// ---------------------------------------------------------------------------
// LSTM forecaster: 2-layer encoder (T=20) + 2-layer decoder (T=30, feedback).
// B=16384, H=128, F=10. R8: R4's shape (256 blocks x 64 batch, 8 waves,
// wave = 4 m-tiles x 4 n-tiles -> B-load:MFMA 1:4) with INTRINSIC MFMA
// (R7's inline-asm MFMA caused data hazards -> absmax 5.6e-3; LLVM's hazard
// recognizer can't see inside asm). Spill fix: c-state lives in LDS
// (64x132 f32 per layer, +132 stride -> 2-way bank = free), freeing 32 VGPRs
// so live ~118 fits the 8-wave cap of 128 (R1-R6 rule:
// cap = 256/max(attr_min, wg_waves/4)). kk unroll 1 caps b-frags in flight.
// LDS total ~103KB (1 block/CU). Identical fp32 arithmetic to R4 (passed).
// ---------------------------------------------------------------------------

typedef __attribute__((ext_vector_type(8))) short short8;   // 8 x bf16 frag
typedef __attribute__((ext_vector_type(4))) float float4v;  // 4 x f32 acc

#define MFMA16(a, b, c) __builtin_amdgcn_mfma_f32_16x16x32_bf16((a), (b), (c), 0, 0, 0)

__device__ __forceinline__ unsigned short f2bf(float x) {
    unsigned u = __builtin_bit_cast(unsigned, x);
    unsigned r = (u + 0x7FFFu + ((u >> 16) & 1u)) >> 16;  // RNE
    return (unsigned short)r;
}
__device__ __forceinline__ float bf2f(unsigned short b) {
    unsigned u = ((unsigned)b) << 16;
    return __builtin_bit_cast(float, u);
}

#if __has_builtin(__builtin_amdgcn_exp2f)
__device__ __forceinline__ float vexp2(float x) { return __builtin_amdgcn_exp2f(x); }
#else
__device__ __forceinline__ float vexp2(float x) { return exp2f(x); }
#endif
#if __has_builtin(__builtin_amdgcn_rcpf)
__device__ __forceinline__ float vrcp(float x) { return __builtin_amdgcn_rcpf(x); }
#else
__device__ __forceinline__ float vrcp(float x) { return 1.0f / x; }
#endif

__device__ __forceinline__ float sigm(float x) {
    return vrcp(1.0f + vexp2(x * -1.442695040888963f));
}
__device__ __forceinline__ float tanh_(float x) {
    return 1.0f - 2.0f * vrcp(1.0f + vexp2(x * 2.885390081777927f));
}

// ---------------------------------------------------------------------------
// prep kernel: fp32 weights -> bf16, concatenated per-layer [Wih | Whh],
// Wih0 padded 10->32; biases summed AND transposed to [set][j][q] float4;
// decoder-y weights transposed to [j][8].
// ws layout: We0[512][160] | We1[512][256] | Wd0[512][128] | Wd1[512][256]
//            (bf16, 819200 B) | bsT[4][128][4] f32 (8 KB) | wyT[128][8] f32 (4 KB)
// ---------------------------------------------------------------------------
__global__ void prep_kernel(const float* __restrict__ eWih0, const float* __restrict__ eWhh0,
                            const float* __restrict__ ebih0, const float* __restrict__ ebhh0,
                            const float* __restrict__ eWih1, const float* __restrict__ eWhh1,
                            const float* __restrict__ ebih1, const float* __restrict__ ebhh1,
                            const float* __restrict__ dWih0, const float* __restrict__ dWhh0,
                            const float* __restrict__ dbih0, const float* __restrict__ dbhh0,
                            const float* __restrict__ dWih1, const float* __restrict__ dWhh1,
                            const float* __restrict__ dbih1, const float* __restrict__ dbhh1,
                            void* __restrict__ ws)
{
    int i = blockIdx.x * 256 + threadIdx.x;
    short* We0 = (short*)ws;
    short* We1 = We0 + 512 * 160;
    short* Wd0 = We1 + 512 * 256;
    short* Wd1 = Wd0 + 512 * 128;
    float* bsT = (float*)((char*)ws + 819200);
    float* wyT = bsT + 2048;
    const int N0 = 512 * 160, N1 = 512 * 256, N2 = 512 * 128, N3 = 512 * 256;
    if (i < N0) {
        int n = i / 160, k = i - n * 160;
        float v = (k < 32) ? (k < 10 ? eWih0[n * 10 + k] : 0.0f) : eWhh0[n * 128 + (k - 32)];
        We0[i] = (short)f2bf(v);
    } else if (i < N0 + N1) {
        int ii = i - N0, n = ii >> 8, k = ii & 255;
        float v = (k < 128) ? eWih1[n * 128 + k] : eWhh1[n * 128 + (k - 128)];
        We1[ii] = (short)f2bf(v);
    } else if (i < N0 + N1 + N2) {
        int ii = i - (N0 + N1);
        Wd0[ii] = (short)f2bf(dWhh0[ii]);
    } else if (i < N0 + N1 + N2 + N3) {
        int ii = i - (N0 + N1 + N2), n = ii >> 8, k = ii & 255;
        float v = (k < 128) ? dWih1[n * 128 + k] : dWhh1[n * 128 + (k - 128)];
        Wd1[ii] = (short)f2bf(v);
    } else if (i < N0 + N1 + N2 + N3 + 2048) {
        int ii = i - (N0 + N1 + N2 + N3);
        int set = ii >> 9, r = ii & 511, j = r >> 2, q = r & 3;
        int g = q * 128 + j;
        float v = (set == 0) ? ebih0[g] + ebhh0[g]
                : (set == 1) ? ebih1[g] + ebhh1[g]
                : (set == 2) ? dbih0[g] + dbhh0[g]
                             : dbih1[g] + dbhh1[g];
        bsT[ii] = v;
    } else if (i < N0 + N1 + N2 + N3 + 2048 + 1024) {
        int ii = i - (N0 + N1 + N2 + N3 + 2048);
        int j = ii >> 3, e = ii & 7, q = e >> 1, cc = e & 1;
        wyT[ii] = dWih0[(q * 128 + j) * 2 + cc];
    }
}

// ---------------------------------------------------------------------------
// main kernel (per block: 64 batch rows, 8 waves)
// LDS h-buffers (64 rows x 16 chunks of 16B): slot(m,kc) = m*16 + (kc ^ (m&15))
// xbuf (64 rows x 4 chunks): slot(m,kc) = m*4 + (kc ^ (m&3))
// c-state in LDS: cbuf[m*132 + j] (stride 132 -> quad pairs 2-way banks, free)
// Wave w: m-tiles {0..3}, n-tiles {w, w+8, w+16, w+24} (q = gate i/f/g/o)
// A-frag: A[m = mt*16 + (lane&15)][k = (lane>>4)*8 + i]
// B-frag: B row n = 16*(w+8q) + (lane&15), k-chunk (lane>>4)
// C/D:    col = lane&15 (gate unit), row = (lane>>4)*4 + reg (batch)
// ---------------------------------------------------------------------------

template <int NKT>
__device__ __forceinline__ void mma4(float4v acc[4][4], const short8* __restrict__ hb,
                                     const char* __restrict__ wb, const unsigned* wo,
                                     int woff, int nib, int quad)
{
#pragma unroll 1
    for (int kk = 0; kk < NKT; ++kk) {
        int sx = ((kk * 4 + quad) ^ nib) + nib * 16;
        short8 a0 = hb[sx];
        short8 a1 = hb[256 + sx];
        short8 a2 = hb[512 + sx];
        short8 a3 = hb[768 + sx];
        short8 b0 = *(const short8*)(wb + (wo[0] + woff + kk * 64));
        short8 b1 = *(const short8*)(wb + (wo[1] + woff + kk * 64));
        short8 b2 = *(const short8*)(wb + (wo[2] + woff + kk * 64));
        short8 b3 = *(const short8*)(wb + (wo[3] + woff + kk * 64));
        acc[0][0] = MFMA16(a0, b0, acc[0][0]);
        acc[0][1] = MFMA16(a1, b0, acc[0][1]);
        acc[0][2] = MFMA16(a2, b0, acc[0][2]);
        acc[0][3] = MFMA16(a3, b0, acc[0][3]);
        acc[1][0] = MFMA16(a0, b1, acc[1][0]);
        acc[1][1] = MFMA16(a1, b1, acc[1][1]);
        acc[1][2] = MFMA16(a2, b1, acc[1][2]);
        acc[1][3] = MFMA16(a3, b1, acc[1][3]);
        acc[2][0] = MFMA16(a0, b2, acc[2][0]);
        acc[2][1] = MFMA16(a1, b2, acc[2][1]);
        acc[2][2] = MFMA16(a2, b2, acc[2][2]);
        acc[2][3] = MFMA16(a3, b2, acc[2][3]);
        acc[3][0] = MFMA16(a0, b3, acc[3][0]);
        acc[3][1] = MFMA16(a1, b3, acc[3][1]);
        acc[3][2] = MFMA16(a2, b3, acc[3][2]);
        acc[3][3] = MFMA16(a3, b3, acc[3][3]);
    }
}

// elementwise LSTM cell update; c-state in LDS (cbase), h (bf16) to hdst
template <bool DEC0>
__device__ __forceinline__ void cell_update4(float4v acc[4][4], float4v bv,
                                             float* __restrict__ cbase,
                                             unsigned short* __restrict__ hdst,
                                             const float* __restrict__ ybuf,
                                             float4v wy0, float4v wy1,
                                             int j, int quad)
{
    int kc = j >> 3;
    int jl = j & 7;
#pragma unroll
    for (int mt = 0; mt < 4; ++mt) {
#pragma unroll
        for (int r = 0; r < 4; ++r) {
            float gi = acc[0][mt][r] + bv[0];
            float gf = acc[1][mt][r] + bv[1];
            float gg = acc[2][mt][r] + bv[2];
            float go = acc[3][mt][r] + bv[3];
            int m = mt * 16 + quad * 4 + r;
            if (DEC0) {
                float y0 = ybuf[2 * m], y1 = ybuf[2 * m + 1];
                gi += y0 * wy0[0] + y1 * wy0[1];
                gf += y0 * wy0[2] + y1 * wy0[3];
                gg += y0 * wy1[0] + y1 * wy1[1];
                go += y0 * wy1[2] + y1 * wy1[3];
            }
            float si = sigm(gi);
            float sf = sigm(gf);
            float tg = tanh_(gg);
            float so = sigm(go);
            float* cp = cbase + (m * 132 + j);
            float c = sf * (*cp) + si * tg;
            *cp = c;
            float h = so * tanh_(c);
            int slot = m * 16 + (kc ^ (m & 15));
            hdst[slot * 8 + jl] = f2bf(h);
        }
    }
}

__global__ void __attribute__((amdgpu_flat_work_group_size(512, 512), amdgpu_waves_per_eu(2)))
lstm_main(
    const float* __restrict__ hist,
    const float* __restrict__ headW, const float* __restrict__ headB,
    const int* __restrict__ futlen, const void* __restrict__ ws,
    float* __restrict__ out)
{
    __shared__ short8 h0buf[1024];   // 64 rows x 16 chunks, swizzled (16 KB)
    __shared__ short8 h1buf[1024];   // 16 KB
    __shared__ short8 xbuf[256];     // 64 rows x 4 chunks, swizzled (4 KB)
    __shared__ float ybuf[128];      // [64][2]
    __shared__ float cbuf0[64 * 132];  // c-state layer 0 (33 KB), pad 132
    __shared__ float cbuf1[64 * 132];  // c-state layer 1 (33 KB)

    const char* wsb = (const char*)ws;
    const char* We0 = wsb;                       // rows of 320 B
    const char* We1 = wsb + 512 * 160 * 2;       // rows of 512 B
    const char* Wd0 = We1 + 512 * 256 * 2;       // rows of 256 B
    const char* Wd1 = Wd0 + 512 * 128 * 2;       // rows of 512 B
    const float* bsT = (const float*)(wsb + 819200);
    const float* wyT = bsT + 2048;

    const int tid = threadIdx.x;
    const int w = tid >> 6;
    const int lane = tid & 63;
    const int quad = lane >> 4;
    const int nib = lane & 15;
    const int b0 = blockIdx.x * 64;
    const int TFUT = *futlen;
    const int j = 16 * w + nib;

    // zero-init LDS state
    h0buf[tid] = (short8)0;
    h0buf[512 + tid] = (short8)0;
    h1buf[tid] = (short8)0;
    h1buf[512 + tid] = (short8)0;
    if (tid < 256) xbuf[tid] = (short8)0;
    if (tid < 128) ybuf[tid] = 0.0f;
    for (int i = tid; i < 64 * 132; i += 512) {
        cbuf0[i] = 0.0f;
        cbuf1[i] = 0.0f;
    }

    // 32-bit B-row byte offsets (per lane): row = 16*(w+8q)+nib, + quad*16
    // eo1 also serves decoder layer 1 (Wd1 has the same 512-B row stride).
    unsigned eo0[4], eo1[4];
#pragma unroll
    for (int q = 0; q < 4; ++q) {
        unsigned row = 16u * (w + 8 * q) + nib;
        eo0[q] = row * 320u + quad * 16u;
        eo1[q] = row * 512u + quad * 16u;
    }
    __syncthreads();

    // ================= ENCODER =================
#pragma unroll 1
    for (int t = 0; t < 20; ++t) {
        // stage hist[.., t, :] -> xbuf (bf16, zero-padded to K=32)
        if (tid < 128) {
            int m = tid & 63, part = tid >> 6;  // part: k-chunk 0 or 1
            const float* hp = hist + ((size_t)((b0 + m) * 20 + t)) * 10;
            float v[8];
            if (part == 0) {
#pragma unroll
                for (int i = 0; i < 8; ++i) v[i] = hp[i];
            } else {
                v[0] = hp[8]; v[1] = hp[9];
#pragma unroll
                for (int i = 2; i < 8; ++i) v[i] = 0.0f;
            }
            short8 pk;
#pragma unroll
            for (int i = 0; i < 8; ++i) pk[i] = (short)f2bf(v[i]);
            xbuf[m * 4 + (part ^ (m & 3))] = pk;
        }
        __syncthreads();

        // ---- layer 0: gates = x@Wih0^T + h0@Whh0^T ----
        {
            float4v acc[4][4];
#pragma unroll
            for (int q = 0; q < 4; ++q)
#pragma unroll
                for (int mt = 0; mt < 4; ++mt) acc[q][mt] = (float4v){0.f, 0.f, 0.f, 0.f};
            // x part (k 0..31) from xbuf
            {
                int sxx = (quad ^ (nib & 3)) + nib * 4;
                short8 a0 = xbuf[sxx];
                short8 a1 = xbuf[64 + sxx];
                short8 a2 = xbuf[128 + sxx];
                short8 a3 = xbuf[192 + sxx];
                short8 bq0 = *(const short8*)(We0 + eo0[0]);
                short8 bq1 = *(const short8*)(We0 + eo0[1]);
                short8 bq2 = *(const short8*)(We0 + eo0[2]);
                short8 bq3 = *(const short8*)(We0 + eo0[3]);
                acc[0][0] = MFMA16(a0, bq0, acc[0][0]);
                acc[0][1] = MFMA16(a1, bq0, acc[0][1]);
                acc[0][2] = MFMA16(a2, bq0, acc[0][2]);
                acc[0][3] = MFMA16(a3, bq0, acc[0][3]);
                acc[1][0] = MFMA16(a0, bq1, acc[1][0]);
                acc[1][1] = MFMA16(a1, bq1, acc[1][1]);
                acc[1][2] = MFMA16(a2, bq1, acc[1][2]);
                acc[1][3] = MFMA16(a3, bq1, acc[1][3]);
                acc[2][0] = MFMA16(a0, bq2, acc[2][0]);
                acc[2][1] = MFMA16(a1, bq2, acc[2][1]);
                acc[2][2] = MFMA16(a2, bq2, acc[2][2]);
                acc[2][3] = MFMA16(a3, bq2, acc[2][3]);
                acc[3][0] = MFMA16(a0, bq3, acc[3][0]);
                acc[3][1] = MFMA16(a1, bq3, acc[3][1]);
                acc[3][2] = MFMA16(a2, bq3, acc[3][2]);
                acc[3][3] = MFMA16(a3, bq3, acc[3][3]);
            }
            // h part (W k 32..159, bytes 64..) from h0buf
            mma4<4>(acc, h0buf, We0, eo0, 64, nib, quad);
            float4v bv = *(const float4v*)(bsT + 0 * 512 + j * 4);
            __syncthreads();
            cell_update4<false>(acc, bv, cbuf0, (unsigned short*)h0buf, nullptr,
                                (float4v){0, 0, 0, 0}, (float4v){0, 0, 0, 0}, j, quad);
        }
        __syncthreads();

        // ---- layer 1: gates = h0new@Wih1^T + h1@Whh1^T ----
        {
            float4v acc[4][4];
#pragma unroll
            for (int q = 0; q < 4; ++q)
#pragma unroll
                for (int mt = 0; mt < 4; ++mt) acc[q][mt] = (float4v){0.f, 0.f, 0.f, 0.f};
            mma4<4>(acc, h0buf, We1, eo1, 0, nib, quad);
            mma4<4>(acc, h1buf, We1, eo1, 256, nib, quad);
            float4v bv = *(const float4v*)(bsT + 1 * 512 + j * 4);
            __syncthreads();
            cell_update4<false>(acc, bv, cbuf1, (unsigned short*)h1buf, nullptr,
                                (float4v){0, 0, 0, 0}, (float4v){0, 0, 0, 0}, j, quad);
        }
        __syncthreads();
    }

    // ================= DECODER =================
    // Wd1 offsets == eo1 (same 512-B stride). Only Wd0 (256-B rows) is new.
    unsigned do0[4];
#pragma unroll
    for (int q = 0; q < 4; ++q) {
        unsigned row = 16u * (w + 8 * q) + nib;
        do0[q] = row * 256u + quad * 16u;
    }

#pragma unroll 1
    for (int t = 0; t < TFUT; ++t) {
        // ---- dec layer 0: gates = y@dWih0^T (VALU) + h0@dWhh0^T (MFMA) ----
        {
            float4v acc[4][4];
#pragma unroll
            for (int q = 0; q < 4; ++q)
#pragma unroll
                for (int mt = 0; mt < 4; ++mt) acc[q][mt] = (float4v){0.f, 0.f, 0.f, 0.f};
            mma4<4>(acc, h0buf, Wd0, do0, 0, nib, quad);
            float4v bv = *(const float4v*)(bsT + 2 * 512 + j * 4);
            float4v wy0 = *(const float4v*)(wyT + j * 8);
            float4v wy1 = *(const float4v*)(wyT + j * 8 + 4);
            __syncthreads();
            cell_update4<true>(acc, bv, cbuf0, (unsigned short*)h0buf, ybuf, wy0, wy1, j, quad);
        }
        __syncthreads();

        // ---- dec layer 1 ----
        {
            float4v acc[4][4];
#pragma unroll
            for (int q = 0; q < 4; ++q)
#pragma unroll
                for (int mt = 0; mt < 4; ++mt) acc[q][mt] = (float4v){0.f, 0.f, 0.f, 0.f};
            mma4<4>(acc, h0buf, Wd1, eo1, 0, nib, quad);
            mma4<4>(acc, h1buf, Wd1, eo1, 256, nib, quad);
            float4v bv = *(const float4v*)(bsT + 3 * 512 + j * 4);
            __syncthreads();
            cell_update4<false>(acc, bv, cbuf1, (unsigned short*)h1buf, nullptr,
                                (float4v){0, 0, 0, 0}, (float4v){0, 0, 0, 0}, j, quad);
        }
        __syncthreads();

        // ---- head: y = h1new @ headW^T + headB; emit output & feedback ----
        if (tid < 128) {
            int m = tid & 63, jj = tid >> 6;
            const float4v* hw = (const float4v*)(headW + jj * 128);
            float dot = headB[jj];
            int mk = m & 15;
#pragma unroll
            for (int kc = 0; kc < 16; ++kc) {
                short8 ch = h1buf[m * 16 + (kc ^ mk)];
                float4v w0 = hw[kc * 2], w1 = hw[kc * 2 + 1];
                dot += bf2f((unsigned short)ch[0]) * w0[0];
                dot += bf2f((unsigned short)ch[1]) * w0[1];
                dot += bf2f((unsigned short)ch[2]) * w0[2];
                dot += bf2f((unsigned short)ch[3]) * w0[3];
                dot += bf2f((unsigned short)ch[4]) * w1[0];
                dot += bf2f((unsigned short)ch[5]) * w1[1];
                dot += bf2f((unsigned short)ch[6]) * w1[2];
                dot += bf2f((unsigned short)ch[7]) * w1[3];
            }
            ybuf[2 * m + jj] = dot;
            out[((size_t)(b0 + m) * TFUT + t) * 2 + jj] = dot;
        }
        __syncthreads();
    }
}

extern "C" void kernel_launch(void* const* d_in, const int* in_sizes, int n_in,
                              void* d_out, int out_size, void* d_ws, size_t ws_size,
                              hipStream_t stream)
{
    const float* hist   = (const float*)d_in[0];
    const float* eWih0  = (const float*)d_in[1];
    const float* eWhh0  = (const float*)d_in[2];
    const float* ebih0  = (const float*)d_in[3];
    const float* ebhh0  = (const float*)d_in[4];
    const float* eWih1  = (const float*)d_in[5];
    const float* eWhh1  = (const float*)d_in[6];
    const float* ebih1  = (const float*)d_in[7];
    const float* ebhh1  = (const float*)d_in[8];
    const float* dWih0  = (const float*)d_in[9];
    const float* dWhh0  = (const float*)d_in[10];
    const float* dbih0  = (const float*)d_in[11];
    const float* dbhh0  = (const float*)d_in[12];
    const float* dWih1  = (const float*)d_in[13];
    const float* dWhh1  = (const float*)d_in[14];
    const float* dbih1  = (const float*)d_in[15];
    const float* dbhh1  = (const float*)d_in[16];
    const float* headW  = (const float*)d_in[17];
    const float* headB  = (const float*)d_in[18];
    const int*   futlen = (const int*)d_in[19];

    // weights 409600 bf16 + bsT 2048 f32 + wyT 1024 f32 -> 412672 work items
    prep_kernel<<<1612, 256, 0, stream>>>(eWih0, eWhh0, ebih0, ebhh0,
                                          eWih1, eWhh1, ebih1, ebhh1,
                                          dWih0, dWhh0, dbih0, dbhh0,
                                          dWih1, dWhh1, dbih1, dbhh1, d_ws);

    lstm_main<<<256, 512, 0, stream>>>(hist, headW, headB, futlen,
                                       d_ws, (float*)d_out);
}